// Round 5
// baseline (108.276 us; speedup 1.0000x reference)
//
#include <hip/hip_runtime.h>

// 8-level sym8 wavelet packet transform, B=128 rows of L0=65536, f32.
// 3 fused kernels: F01 (levels 0-1), F23 (levels 2-3), F47 (levels 4-7).
// Level lengths: 65536->32775->16395->8205->4110->2062->1038->526->270.
// 512 threads/block, ~35.3 KB LDS -> 4 blocks/CU -> 32 waves/CU.
// Scratch rows padded to x4 stride (16396 / 4112) for float4 global I/O.

#define PHI(i) ((i) + ((i) >> 4))
#define BT 512

// fl[t] = dec_lo[15-t]  (flipped low-pass, cross-correlation form)
__device__ __constant__ float FL[16] = {
     0.0018899503327594609f, -0.0003029205147213668f, -0.01495225833704823f,
     0.003808752013890615f,   0.049137179673607506f,  -0.027219029917056003f,
    -0.05194583810770904f,    0.3644418948353314f,     0.7771857517005235f,
     0.4813596512583722f,    -0.061273359067658524f,  -0.1432942383508097f,
     0.007607487324917605f,   0.03169508781149298f,   -0.0005421323317911481f,
    -0.0033824159510061256f
};

// fh[t] = dec_hi[15-t] = (t odd ? +1 : -1) * dec_lo[t]
__device__ __constant__ float FH[16] = {
     0.0033824159510061256f, -0.0005421323317911481f, -0.03169508781149298f,
     0.007607487324917605f,   0.1432942383508097f,    -0.061273359067658524f,
    -0.4813596512583722f,     0.7771857517005235f,    -0.3644418948353314f,
    -0.05194583810770904f,    0.027219029917056003f,   0.049137179673607506f,
    -0.003808752013890615f,  -0.01495225833704823f,    0.0003029205147213668f,
     0.0018899503327594609f
};

// ---------------- Fused two-level kernel (levels k, k+1) ----------------
// SIN/SOUT: padded row strides. Block = (row n, segment of MB=1028 B-outputs).
template <int LIN, int LA, int LB, int SIN, int SOUT>
__global__ __launch_bounds__(BT, 8) void dwt_pair(
    const float* __restrict__ x, float* __restrict__ y) {
    constexpr int MB = 1028;
    constexpr int WA = 2 * MB + 14;   // 2070
    constexpr int WX = 2 * WA + 14;   // 4154
    constexpr int GJ = MB / 4;        // 257 B-groups per subband
    __shared__ float xs[PHI(WX) + 2];
    __shared__ float as[PHI(2 * WA) + 2];

    const int seg = blockIdx.x;
    const int n   = blockIdx.y;
    const int b0  = seg * MB;

    int a_lo = 2 * b0 - 14;
    if (a_lo < 0) a_lo = 0;
    if (a_lo > LA - WA) a_lo = LA - WA;
    const int px0 = 2 * a_lo - 14;

    const float* row = x + (size_t)n * (size_t)SIN;

    // x-tile fill (coalesced; float2 interior, reflect-folded scalar at edges)
    if (px0 >= 0 && px0 + WX <= LIN) {
        const float2* rp = reinterpret_cast<const float2*>(row + px0);
        for (int h = threadIdx.x; h < WX / 2; h += BT) {
            const float2 v = rp[h];
            xs[PHI(2 * h)]     = v.x;
            xs[PHI(2 * h + 1)] = v.y;
        }
    } else {
        for (int p = threadIdx.x; p < WX; p += BT) {
            int q = px0 + p;
            q = (q < 0) ? -q : q;
            q = (q >= LIN) ? (2 * LIN - 2 - q) : q;
            xs[PHI(p)] = row[q];
        }
    }
    __syncthreads();

    // A-phase: genuine positions s in [0, WA), two per thread, both filters
    for (int g = threadIdx.x; g < WA / 2; g += BT) {
        const int s0 = 2 * g;
        float w[18];
#pragma unroll
        for (int t = 0; t < 18; ++t) w[t] = xs[PHI(2 * s0 + t)];
        float lo0 = 0.f, hi0 = 0.f, lo1 = 0.f, hi1 = 0.f;
#pragma unroll
        for (int t = 0; t < 16; ++t) {
            const float cl = FL[t], ch = FH[t];
            lo0 = fmaf(w[t],     cl, lo0);
            hi0 = fmaf(w[t],     ch, hi0);
            lo1 = fmaf(w[t + 2], cl, lo1);
            hi1 = fmaf(w[t + 2], ch, hi1);
        }
        as[PHI(s0)]          = lo0;
        as[PHI(s0 + 1)]      = lo1;
        as[PHI(WA + s0)]     = hi0;
        as[PHI(WA + s0 + 1)] = hi1;
    }
    __syncthreads();

    // B-phase: 2*GJ groups of 4 consecutive j
    for (int g = threadIdx.x; g < 2 * GJ; g += BT) {
        const int sA = (g >= GJ) ? 1 : 0;
        const int gj = g - sA * GJ;
        const int j0 = b0 + gj * 4;
        if (j0 >= LB) continue;

        const int q0 = 2 * j0 - 14;
        const int aBase = sA * WA - a_lo;
        float w[22];
        if (q0 >= a_lo && q0 + 22 <= a_lo + WA) {
#pragma unroll
            for (int t = 0; t < 22; ++t) w[t] = as[PHI(aBase + q0 + t)];
        } else {
#pragma unroll
            for (int t = 0; t < 22; ++t) {
                int q = q0 + t;
                q = (q < 0) ? -q : q;
                q = (q >= LA) ? (2 * LA - 2 - q) : q;
                w[t] = as[PHI(aBase + q)];
            }
        }

        float lo[4], hi[4];
#pragma unroll
        for (int i = 0; i < 4; ++i) { lo[i] = 0.f; hi[i] = 0.f; }
#pragma unroll
        for (int t = 0; t < 16; ++t) {
            const float cl = FL[t], ch = FH[t];
#pragma unroll
            for (int i = 0; i < 4; ++i) {
                const float v = w[2 * i + t];
                lo[i] = fmaf(v, cl, lo[i]);
                hi[i] = fmaf(v, ch, hi[i]);
            }
        }

        float* y0 = y + (size_t)(4 * n + 2 * sA) * (size_t)SOUT + (size_t)j0;
        float* y1 = y0 + SOUT;
        if (j0 + 3 < LB) {  // aligned: SOUT % 4 == 0, j0 % 4 == 0
            *reinterpret_cast<float4*>(y0) = make_float4(lo[0], lo[1], lo[2], lo[3]);
            *reinterpret_cast<float4*>(y1) = make_float4(hi[0], hi[1], hi[2], hi[3]);
        } else {
#pragma unroll
            for (int i = 0; i < 4; ++i)
                if (j0 + i < LB) { y0[i] = lo[i]; y1[i] = hi[i]; }
        }
    }
}

// ---------------- Fused four-level kernel (levels 4-7) ----------------
template <int LIN, int P, bool LOG>
__device__ __forceinline__ void f47_stage(const float* __restrict__ in,
                                          float* __restrict__ outl,
                                          float* __restrict__ outg) {
    constexpr int LOUT = LIN / 2 + 7;
    constexpr int GPC = (LOUT + 3) / 4;
    constexpr int G = P * GPC;
    for (int g = threadIdx.x; g < G; g += BT) {
        const int p  = g / GPC;            // compile-time divisor
        const int jg = g - p * GPC;
        const int j0 = jg * 4;
        const int q0 = 2 * j0 - 14;
        const int ib = p * LIN;

        float w[22];
        if (q0 >= 0 && q0 + 22 <= LIN) {
#pragma unroll
            for (int t = 0; t < 22; ++t) w[t] = in[PHI(ib + q0 + t)];
        } else {
#pragma unroll
            for (int t = 0; t < 22; ++t) {
                int q = q0 + t;
                q = (q < 0) ? -q : q;
                q = (q >= LIN) ? (2 * LIN - 2 - q) : q;
                w[t] = in[PHI(ib + q)];
            }
        }

        float lo[4], hi[4];
#pragma unroll
        for (int i = 0; i < 4; ++i) { lo[i] = 0.f; hi[i] = 0.f; }
#pragma unroll
        for (int t = 0; t < 16; ++t) {
            const float cl = FL[t], ch = FH[t];
#pragma unroll
            for (int i = 0; i < 4; ++i) {
                const float v = w[2 * i + t];
                lo[i] = fmaf(v, cl, lo[i]);
                hi[i] = fmaf(v, ch, hi[i]);
            }
        }

        const int ob0 = (2 * p) * LOUT;
        const int ob1 = ob0 + LOUT;
#pragma unroll
        for (int i = 0; i < 4; ++i) {
            if (j0 + i < LOUT) {
                if (LOG) {
                    outg[ob0 + j0 + i] = __logf(fmaf(lo[i], lo[i], 1e-12f));
                    outg[ob1 + j0 + i] = __logf(fmaf(hi[i], hi[i], 1e-12f));
                } else {
                    outl[PHI(ob0 + j0 + i)] = lo[i];
                    outl[PHI(ob1 + j0 + i)] = hi[i];
                }
            }
        }
    }
}

__global__ __launch_bounds__(BT, 8) void dwt_quad(
    const float* __restrict__ x, float* __restrict__ y) {
    __shared__ float bufA[PHI(4152) + 2];  // input 4110(+2 pad), lev5 out 4x1038
    __shared__ float bufB[PHI(4208) + 2];  // lev4 out 2x2062, lev6 out 8x526

    const int m = blockIdx.x;
    const float4* row4 = reinterpret_cast<const float4*>(x + (size_t)m * 4112);
    for (int h = threadIdx.x; h < 1028; h += BT) {  // 4112 floats (last 2 junk, never read)
        const float4 v = row4[h];
        const int p = 4 * h;
        bufA[PHI(p)]     = v.x;
        bufA[PHI(p + 1)] = v.y;
        bufA[PHI(p + 2)] = v.z;
        bufA[PHI(p + 3)] = v.w;
    }
    __syncthreads();

    f47_stage<4110, 1, false>(bufA, bufB, nullptr);  // -> 2x2062
    __syncthreads();
    f47_stage<2062, 2, false>(bufB, bufA, nullptr);  // -> 4x1038
    __syncthreads();
    f47_stage<1038, 4, false>(bufA, bufB, nullptr);  // -> 8x526
    __syncthreads();
    float* out = y + (size_t)m * (16 * 270);
    f47_stage<526, 8, true>(bufB, nullptr, out);     // -> 16x270 + log
}

extern "C" void kernel_launch(void* const* d_in, const int* in_sizes, int n_in,
                              void* d_out, int out_size, void* d_ws, size_t ws_size,
                              hipStream_t stream) {
    const float* in = (const float*)d_in[0];
    float* out = (float*)d_out;
    float* wsA = (float*)d_ws;                  // lev1: 512 rows, stride 16396 (~33.6 MB)
    float* wsB = (float*)d_ws + 8400000;        // lev3: 2048 rows, stride 4112 (~33.7 MB)

    // F01: 65536 -> 32775 -> 16395; 128 rows -> 512 subrows
    { dim3 g(16, 128); dwt_pair<65536, 32775, 16395, 65536, 16396><<<g, BT, 0, stream>>>(in, wsA); }
    // F23: 16395 -> 8205 -> 4110; 512 subrows -> 2048 subrows
    { dim3 g(4, 512);  dwt_pair<16395, 8205, 4110, 16396, 4112><<<g, BT, 0, stream>>>(wsA, wsB); }
    // F47: 4110 -> 2062 -> 1038 -> 526 -> 270(+log); 2048 subrows -> 32768 rows
    dwt_quad<<<2048, BT, 0, stream>>>(wsB, out);
}

// Round 7
// 90.676 us; speedup vs baseline: 1.1941x; 1.1941x over previous
//
#include <hip/hip_runtime.h>

// 8-level sym8 wavelet packet transform, B=128 rows of L0=65536, f32.
// 3 fused kernels: F01 (levels 0-1), F23 (levels 2-3), F47 (levels 4-7).
// Lengths: 65536->32775->16395->8205->4110->2062->1038->526->270.
// NO=2 interleaved work mapping: thread group u owns outputs (2u, 2u+1);
// window base = 4u words (16B aligned) -> 5x ds_read_b128, immediate offsets,
// dense conflict-free bank pattern. Branch-free inner loops: pair kernels use
// a virtual (reflect-at-build) A-tile; quad uses mirrored 14-float margins on
// every subrow buffer (mirror_put takes the EXT BASE pointer — R5 bug was
// passing the genuine-origin pointer here, corrupting edges).

#define BT 512

// fl[t] = dec_lo[15-t]  (flipped low-pass, cross-correlation form)
__device__ __constant__ float FL[16] = {
     0.0018899503327594609f, -0.0003029205147213668f, -0.01495225833704823f,
     0.003808752013890615f,   0.049137179673607506f,  -0.027219029917056003f,
    -0.05194583810770904f,    0.3644418948353314f,     0.7771857517005235f,
     0.4813596512583722f,    -0.061273359067658524f,  -0.1432942383508097f,
     0.007607487324917605f,   0.03169508781149298f,   -0.0005421323317911481f,
    -0.0033824159510061256f
};

// fh[t] = dec_hi[15-t] = (t odd ? +1 : -1) * dec_lo[t]
__device__ __constant__ float FH[16] = {
     0.0033824159510061256f, -0.0005421323317911481f, -0.03169508781149298f,
     0.007607487324917605f,   0.1432942383508097f,    -0.061273359067658524f,
    -0.4813596512583722f,     0.7771857517005235f,    -0.3644418948353314f,
    -0.05194583810770904f,    0.027219029917056003f,   0.049137179673607506f,
    -0.003808752013890615f,  -0.01495225833704823f,    0.0003029205147213668f,
     0.0018899503327594609f
};

// Load 20-float window from LDS: 5 x ds_read_b128 (base must be mult of 4).
__device__ __forceinline__ void load20(const float* __restrict__ lds, int base,
                                       float w[20]) {
#pragma unroll
    for (int k = 0; k < 5; ++k) {
        const float4 v = *reinterpret_cast<const float4*>(&lds[base + 4 * k]);
        w[4 * k] = v.x; w[4 * k + 1] = v.y; w[4 * k + 2] = v.z; w[4 * k + 3] = v.w;
    }
}

// Convolve positions (j, j+1) with both filters from an 18-tap window.
__device__ __forceinline__ void conv2(const float w[20], float& lo0, float& hi0,
                                      float& lo1, float& hi1) {
    lo0 = hi0 = lo1 = hi1 = 0.f;
#pragma unroll
    for (int t = 0; t < 16; ++t) {
        const float cl = FL[t], ch = FH[t];
        lo0 = fmaf(w[t], cl, lo0);
        hi0 = fmaf(w[t], ch, hi0);
        lo1 = fmaf(w[t + 2], cl, lo1);
        hi1 = fmaf(w[t + 2], ch, hi1);
    }
}

// Mirror write into an ext buffer. ext = EXT BASE (genuine j lives at ext[14+j]).
__device__ __forceinline__ void mirror_put(float* ext, int LOUTc, int j, float v) {
    if (j >= 1 && j <= 14) ext[14 - j] = v;
    if (j >= LOUTc - 15 && j <= LOUTc - 2) ext[2 * LOUTc + 12 - j] = v;
}

// ---------------- Fused two-level kernel (levels k, k+1) ----------------
template <int LIN, int LA, int LB, int SIN, int SOUT, int MB>
__global__ __launch_bounds__(BT, 8) void dwt_pair(
    const float* __restrict__ x, float* __restrict__ y) {
    constexpr int WA  = 2 * MB + 14;                 // virtual A-tile width (even)
    constexpr int WAp = (WA + 2 + 3) & ~3;           // subband stride (mult 4, +pad)
    constexpr int WX  = 2 * WA + 14;                 // x-tile width (even)
    constexpr int WXp = (WX + 2 + 3) & ~3;           // with b128 over-read pad
    constexpr int PP  = WA / 2;                      // A-phase pairs
    constexpr int GH  = MB / 2;                      // B-phase pairs per subband
    __shared__ float xs[WXp];
    __shared__ float as[2 * WAp];

    const int seg = blockIdx.x;
    const int n   = blockIdx.y;
    const int b0  = seg * MB;
    const int a_lo = 2 * b0 - 14;        // virtual tile start (may be <0 / >LA-WA)
    const int px0  = 2 * a_lo - 14;      // x coordinate of xs[0] (always even)

    const float* row = x + (size_t)n * (size_t)SIN;

    // ---- x-tile fill ----
    if (px0 >= 0 && px0 + WX <= LIN) {
        const float2* rp = reinterpret_cast<const float2*>(row + px0);
        for (int h = threadIdx.x; h < WX / 2; h += BT) {
            *reinterpret_cast<float2*>(&xs[2 * h]) = rp[h];
        }
    } else {
        for (int p = threadIdx.x; p < WX; p += BT) {
            int q = px0 + p;
            q = (q < 0) ? -q : q;
            q = (q >= LIN) ? (2 * LIN - 2 - q) : q;
            xs[p] = row[q];
        }
    }
    __syncthreads();

    // ---- A-phase: virtual positions a_lo+s, s in [0, WA) ----
    for (int g = threadIdx.x; g < PP; g += BT) {
        const int s0 = 2 * g;
        const int a  = a_lo + s0;
        float lo0, hi0, lo1, hi1;
        if (a >= 0 && a + 1 < LA) {
            float w[20];
            load20(xs, 4 * g, w);        // rel window = [2*s0, 2*s0+17]
            conv2(w, lo0, hi0, lo1, hi1);
        } else {
#pragma unroll
            for (int e = 0; e < 2; ++e) {
                int ga = a + e;
                ga = (ga < 0) ? -ga : ga;
                ga = (ga >= LA) ? (2 * LA - 2 - ga) : ga;
                const int bb = 2 * ga - 14 - px0;    // even, in-range
                float l = 0.f, h = 0.f;
#pragma unroll
                for (int t = 0; t < 16; ++t) {
                    const float v = xs[bb + t];
                    l = fmaf(v, FL[t], l);
                    h = fmaf(v, FH[t], h);
                }
                if (e == 0) { lo0 = l; hi0 = h; } else { lo1 = l; hi1 = h; }
            }
        }
        *reinterpret_cast<float2*>(&as[s0])       = make_float2(lo0, lo1);
        *reinterpret_cast<float2*>(&as[WAp + s0]) = make_float2(hi0, hi1);
    }
    __syncthreads();

    // ---- B-phase: branch-free (virtual tile covers all reflect cases) ----
    for (int g = threadIdx.x; g < MB; g += BT) {
        const int sA = (g >= GH) ? 1 : 0;
        const int u  = g - sA * GH;
        const int j0 = b0 + 2 * u;
        if (j0 >= LB) continue;
        float w[20];
        load20(as, sA * WAp + 4 * u, w);             // rel = q0 - a_lo = 4u
        float lo0, hi0, lo1, hi1;
        conv2(w, lo0, hi0, lo1, hi1);
        float* y0 = y + (size_t)(4 * n + 2 * sA) * (size_t)SOUT + (size_t)j0;
        float* y1 = y0 + SOUT;
        if (j0 + 1 < LB) {
            *reinterpret_cast<float2*>(y0) = make_float2(lo0, lo1);
            *reinterpret_cast<float2*>(y1) = make_float2(hi0, hi1);
        } else {
            y0[0] = lo0; y1[0] = hi0;
        }
    }
}

// ---------------- Fused four-level kernel (levels 4-7) ----------------
// ext layout per subrow: [14 reflected | LIN genuine | 14 reflected | pad]
// Stage reads taps at ext[p*Sin + 4u + t] (b128, branch-free).
template <int LINs, int P, int Sin, int Sout, bool LOG>
__device__ __forceinline__ void stage(const float* __restrict__ inb,
                                      float* __restrict__ outb,
                                      float* __restrict__ outg) {
    constexpr int LOUT = LINs / 2 + 7;               // even for all our stages
    constexpr int PP   = LOUT / 2;
    for (int g = threadIdx.x; g < P * PP; g += BT) {
        const int p = g / PP;                        // compile-time divisor
        const int u = g - p * PP;
        float w[20];
        load20(inb, p * Sin + 4 * u, w);
        float lo0, hi0, lo1, hi1;
        conv2(w, lo0, hi0, lo1, hi1);
        const int j0 = 2 * u;
        if (LOG) {
            float* o0 = outg + (size_t)(2 * p) * 270 + j0;
            float* o1 = o0 + 270;
            *reinterpret_cast<float2*>(o0) =
                make_float2(__logf(fmaf(lo0, lo0, 1e-12f)),
                            __logf(fmaf(lo1, lo1, 1e-12f)));
            *reinterpret_cast<float2*>(o1) =
                make_float2(__logf(fmaf(hi0, hi0, 1e-12f)),
                            __logf(fmaf(hi1, hi1, 1e-12f)));
        } else {
            float* e0 = outb + (2 * p) * Sout;       // EXT BASE pointers
            float* e1 = e0 + Sout;
            *reinterpret_cast<float2*>(e0 + 14 + j0) = make_float2(lo0, lo1);
            *reinterpret_cast<float2*>(e1 + 14 + j0) = make_float2(hi0, hi1);
            if (j0 <= 14 || j0 >= LOUT - 16) {
                mirror_put(e0, LOUT, j0, lo0);
                mirror_put(e0, LOUT, j0 + 1, lo1);
                mirror_put(e1, LOUT, j0, hi0);
                mirror_put(e1, LOUT, j0 + 1, hi1);
            }
        }
    }
}

__global__ __launch_bounds__(BT, 8) void dwt_quad(
    const float* __restrict__ x, float* __restrict__ y) {
    // ext strides (mult of 4, >= 2*LOUT+16 for b128 over-read)
    constexpr int S1 = 4140, S2 = 2092, S3 = 1068, S4 = 556;
    __shared__ float bufA[4272];   // input ext (4140) | stage2 out 4 x 1068
    __shared__ float bufB[4448];   // stage1 out 2 x 2092 | stage3 out 8 x 556

    const int m = blockIdx.x;
    const float* row = x + (size_t)m * 4112;

    // fill input ext: bufA[14+p] = row[p], p in [0,4110), mirrored margins
    for (int h = threadIdx.x; h < 2055; h += BT) {
        const int p = 2 * h;
        const float2 v = *reinterpret_cast<const float2*>(row + p);
        *reinterpret_cast<float2*>(&bufA[14 + p]) = v;
        if (p <= 14 || p >= 4110 - 16) {
            mirror_put(bufA, 4110, p, v.x);
            mirror_put(bufA, 4110, p + 1, v.y);
        }
    }
    __syncthreads();

    stage<4110, 1, S1, S2, false>(bufA, bufB, nullptr);  // -> 2 x 2062
    __syncthreads();
    stage<2062, 2, S2, S3, false>(bufB, bufA, nullptr);  // -> 4 x 1038
    __syncthreads();
    stage<1038, 4, S3, S4, false>(bufA, bufB, nullptr);  // -> 8 x 526
    __syncthreads();
    stage<526, 8, S4, 0, true>(bufB, nullptr, y + (size_t)m * 4320);  // 16 x 270
}

extern "C" void kernel_launch(void* const* d_in, const int* in_sizes, int n_in,
                              void* d_out, int out_size, void* d_ws, size_t ws_size,
                              hipStream_t stream) {
    const float* in = (const float*)d_in[0];
    float* out = (float*)d_out;
    float* wsA = (float*)d_ws;              // lev1: 512 rows, stride 16396
    float* wsB = (float*)d_ws + 8400000;    // lev3: 2048 rows, stride 4112

    // F01: 65536 -> 32775 -> 16395; MB=1026 -> 16 segs
    { dim3 g(16, 128); dwt_pair<65536, 32775, 16395, 65536, 16396, 1026>
          <<<g, BT, 0, stream>>>(in, wsA); }
    // F23: 16395 -> 8205 -> 4110; MB=1028 -> 4 segs
    { dim3 g(4, 512);  dwt_pair<16395, 8205, 4110, 16396, 4112, 1028>
          <<<g, BT, 0, stream>>>(wsA, wsB); }
    // F47: 4110 -> 2062 -> 1038 -> 526 -> 270(+log)
    dwt_quad<<<2048, BT, 0, stream>>>(wsB, out);
}